// Round 7
// baseline (705.132 us; speedup 1.0000x reference)
//
#include <hip/hip_runtime.h>
#include <hip/hip_bf16.h>

// Problem constants (fixed by setup_inputs)
#define TDIM 4096
#define BDIM 4
#define DDIM 1024
#define HDIM 16
#define HD   64
#define MDIM (TDIM * BDIM)      // 16384 rows (t,b)

typedef __attribute__((ext_vector_type(8))) short short8v;  // 8 bf16 bits = 4 VGPR
typedef __attribute__((ext_vector_type(4))) float f32x4;

__device__ __forceinline__ ushort f2bfu(float f) {
  union { __hip_bfloat16 h; ushort u; } c;
  c.h = __float2bfloat16(f);
  return c.u;
}
__device__ __forceinline__ float bfu2f(ushort u) {
  union { ushort u; __hip_bfloat16 h; } c;
  c.u = u;
  return __bfloat162float(c.h);
}

// async global->LDS, 16B per lane; LDS dest = wave-uniform base + lane*16
#define GLOAD16(gp, lp) __builtin_amdgcn_global_load_lds( \
    (const __attribute__((address_space(1))) void*)(gp),  \
    (__attribute__((address_space(3))) void*)(lp), 16, 0, 0)

// LDS swizzle: g(row) = (row>>1)&3. Bank quad = 4*(row&1) + (slot^g(row))
// is bijective over 8 consecutive rows -> 2 lanes/quad on ds_read_b128 (free).
// Verified r4: SQ_LDS_BANK_CONFLICT 2.5e7 -> 0.
#define SWZ(row) (((row) >> 1) & 3)

// ---------------------------------------------------------------------------
// split fp32 -> bf16 hi/lo arrays (hi = bf16(x), lo = bf16(x - hi))
// ---------------------------------------------------------------------------
__global__ __launch_bounds__(256)
void split_f32(const float* __restrict__ in, ushort* __restrict__ hi,
               ushort* __restrict__ lo, int n4)
{
  int i = blockIdx.x * blockDim.x + threadIdx.x;
  const int stride = gridDim.x * blockDim.x;
  for (; i < n4; i += stride) {
    const float4 v = ((const float4*)in)[i];
    ushort4 h, l;
    h.x = f2bfu(v.x); l.x = f2bfu(v.x - bfu2f(h.x));
    h.y = f2bfu(v.y); l.y = f2bfu(v.y - bfu2f(h.y));
    h.z = f2bfu(v.z); l.z = f2bfu(v.z - bfu2f(h.z));
    h.w = f2bfu(v.w); l.w = f2bfu(v.w - bfu2f(h.w));
    ((ushort4*)hi)[i] = h;
    ((ushort4*)lo)[i] = l;
  }
}

// ---------------------------------------------------------------------------
// GEMM1 (r7): all four operands pre-split bf16 hi/lo, all staged via
// global_load_lds (A-side split VALU + ds_writes removed; r6 post-mortem:
// VALUBusy 36% was mostly A-split conversions).
// Processes an m-half [mbase, mbase+8192) so fp32 Qc/Kc buffers are half-size
// (keeps ws at the proven 226 MiB despite adding Xh/Xl).
// Output: q -> Qc[bh][t_local][64] fp32; k -> Kc; v -> bf16 hi/lo V (full).
// 128x128 tile, BK=32, 4 waves (2x2), each wave 4x4 frags of 16x16x32.
// ---------------------------------------------------------------------------
__global__ __launch_bounds__(256, 2)
void gemm1_mfma(const ushort* __restrict__ Xh, const ushort* __restrict__ Xl,
                const ushort* __restrict__ Wh, const ushort* __restrict__ Wl,
                const float* __restrict__ bias,
                float* __restrict__ Qc, float* __restrict__ Kc,
                ushort* __restrict__ Vh, ushort* __restrict__ Vl, int mbase)
{
  __shared__ ushort sAh[128][32], sAl[128][32], sBh[128][32], sBl[128][32];
  const int tid = threadIdx.x;
  const int lane = tid & 63, wid = tid >> 6;
  const int m0 = mbase + blockIdx.y * 128, n0 = blockIdx.x * 128;
  const int wm = wid >> 1, wn = wid & 1;       // wave grid 2x2
  const int fr = lane & 15, kg = lane >> 4;    // frag row/col, k-group

  f32x4 acc[4][4];
#pragma unroll
  for (int m = 0; m < 4; ++m)
#pragma unroll
    for (int n = 0; n < 4; ++n) acc[m][n] = (f32x4){0.f, 0.f, 0.f, 0.f};

  for (int k0 = 0; k0 < DDIM; k0 += 32) {
    __syncthreads();   // previous iteration's ds_reads done
    // ---- stage: 32 chunks (16 rows x 1KB each), 8 per wave, all gload_lds
#pragma unroll
    for (int j = 0; j < 8; ++j) {
      const int c = wid * 8 + j;
      const int r0 = (c & 7) * 16;
      const int row = r0 + (lane >> 2);
      const int s = lane & 3;
      const int ks = k0 + ((s ^ SWZ(row)) << 3);
      if (c < 8)       GLOAD16(Xh + (size_t)(m0 + row) * DDIM + ks, &sAh[r0][0]);
      else if (c < 16) GLOAD16(Xl + (size_t)(m0 + row) * DDIM + ks, &sAl[r0][0]);
      else if (c < 24) GLOAD16(Wh + (size_t)(n0 + row) * DDIM + ks, &sBh[r0][0]);
      else             GLOAD16(Wl + (size_t)(n0 + row) * DDIM + ks, &sBl[r0][0]);
    }
    __syncthreads();   // drains vmcnt (gload_lds)

    // ---- compute: 16 ds_read_b128 + 48 MFMA per wave ----
    short8v ah[4], al[4], bh[4], bl[4];
#pragma unroll
    for (int m = 0; m < 4; ++m) {
      const int row = wm * 64 + m * 16 + fr;
      const int so = (kg ^ SWZ(row)) << 3;
      ah[m] = *(const short8v*)&sAh[row][so];
      al[m] = *(const short8v*)&sAl[row][so];
    }
#pragma unroll
    for (int n = 0; n < 4; ++n) {
      const int col = wn * 64 + n * 16 + fr;
      const int so = (kg ^ SWZ(col)) << 3;
      bh[n] = *(const short8v*)&sBh[col][so];
      bl[n] = *(const short8v*)&sBl[col][so];
    }
#pragma unroll
    for (int m = 0; m < 4; ++m)
#pragma unroll
      for (int n = 0; n < 4; ++n) {
        acc[m][n] = __builtin_amdgcn_mfma_f32_16x16x32_bf16(ah[m], bh[n], acc[m][n], 0, 0, 0);
        acc[m][n] = __builtin_amdgcn_mfma_f32_16x16x32_bf16(ah[m], bl[n], acc[m][n], 0, 0, 0);
        acc[m][n] = __builtin_amdgcn_mfma_f32_16x16x32_bf16(al[m], bh[n], acc[m][n], 0, 0, 0);
      }
  }

  // ---- epilogue: C/D layout col=lane&15, row=(lane>>4)*4+reg (m89) ----
  const int region = n0 >> 10;   // 0=q, 1=k, 2=v (128-tiles never straddle)
#pragma unroll
  for (int m = 0; m < 4; ++m)
#pragma unroll
    for (int n = 0; n < 4; ++n) {
      const int col = n0 + wn * 64 + n * 16 + fr;
      const float bz = bias[col];
      const int cc = col & 1023;
      const int hh = cc >> 6, dd = cc & 63;
#pragma unroll
      for (int r = 0; r < 4; ++r) {
        const int row = m0 + wm * 64 + m * 16 + kg * 4 + r;
        const float v = acc[m][n][r] + bz;
        const int tl = (row - mbase) >> 2, b = row & 3;  // half-local t
        const size_t ho = (((size_t)(b * 16 + hh)) * 2048 + tl) * 64 + dd;
        if (region == 0)      Qc[ho] = v;
        else if (region == 1) Kc[ho] = v;
        else {
          const size_t o = (size_t)row * 1024 + cc;
          const ushort h2 = f2bfu(v);
          Vh[o] = h2;
          Vl[o] = f2bfu(v - bfu2f(h2));
        }
      }
    }
}

// ---------------------------------------------------------------------------
// GEMM2 (batched over b): out[t,b,:] = v[t,b,:] @ Weff_b^T + bout.
// BM=64, BN=128, grid (8, 64, 4) = 2048 blocks. Unchanged from r6.
// ---------------------------------------------------------------------------
__global__ __launch_bounds__(256, 2)
void gemm2_mfma(const ushort* __restrict__ Vh, const ushort* __restrict__ Vl,
                const ushort* __restrict__ Weh, const ushort* __restrict__ Wel,
                const float* __restrict__ bias, float* __restrict__ Out)
{
  __shared__ ushort sAh[64][32], sAl[64][32], sBh[128][32], sBl[128][32];
  const int tid = threadIdx.x;
  const int lane = tid & 63, wid = tid >> 6;
  const int m0 = blockIdx.y * 64, n0 = blockIdx.x * 128, bb = blockIdx.z;
  const int wm = wid >> 1, wn = wid & 1;
  const int fr = lane & 15, kg = lane >> 4;

  f32x4 acc[2][4];
#pragma unroll
  for (int m = 0; m < 2; ++m)
#pragma unroll
    for (int n = 0; n < 4; ++n) acc[m][n] = (f32x4){0.f, 0.f, 0.f, 0.f};

  const size_t wB = (size_t)bb * DDIM * DDIM;

  for (int k0 = 0; k0 < DDIM; k0 += 32) {
#pragma unroll
    for (int j = 0; j < 6; ++j) {
      const int c = wid * 6 + j;
      const int rl = lane >> 2, s = lane & 3;
      if (c < 8) {
        const int r0 = (c & 3) * 16;
        const int row = r0 + rl;
        const size_t g = (size_t)((m0 + row) * 4 + bb) * 1024 + k0 + ((s ^ SWZ(row)) << 3);
        if (c < 4) GLOAD16(Vh + g, &sAh[r0][0]);
        else       GLOAD16(Vl + g, &sAl[r0][0]);
      } else {
        const int r0 = ((c - 8) & 7) * 16;
        const int row = r0 + rl;
        const size_t g = wB + (size_t)(n0 + row) * 1024 + k0 + ((s ^ SWZ(row)) << 3);
        if (c < 16) GLOAD16(Weh + g, &sBh[r0][0]);
        else        GLOAD16(Wel + g, &sBl[r0][0]);
      }
    }
    __syncthreads();

    short8v ah[2], al[2], bh[4], bl[4];
#pragma unroll
    for (int m = 0; m < 2; ++m) {
      const int row = wm * 32 + m * 16 + fr;
      const int so = (kg ^ SWZ(row)) << 3;
      ah[m] = *(const short8v*)&sAh[row][so];
      al[m] = *(const short8v*)&sAl[row][so];
    }
#pragma unroll
    for (int n = 0; n < 4; ++n) {
      const int col = wn * 64 + n * 16 + fr;
      const int so = (kg ^ SWZ(col)) << 3;
      bh[n] = *(const short8v*)&sBh[col][so];
      bl[n] = *(const short8v*)&sBl[col][so];
    }
#pragma unroll
    for (int m = 0; m < 2; ++m)
#pragma unroll
      for (int n = 0; n < 4; ++n) {
        acc[m][n] = __builtin_amdgcn_mfma_f32_16x16x32_bf16(ah[m], bh[n], acc[m][n], 0, 0, 0);
        acc[m][n] = __builtin_amdgcn_mfma_f32_16x16x32_bf16(ah[m], bl[n], acc[m][n], 0, 0, 0);
        acc[m][n] = __builtin_amdgcn_mfma_f32_16x16x32_bf16(al[m], bh[n], acc[m][n], 0, 0, 0);
      }
    __syncthreads();
  }

  float* Ob = Out + (size_t)bb * 1024;     // row t -> offset t*4096
#pragma unroll
  for (int m = 0; m < 2; ++m)
#pragma unroll
    for (int n = 0; n < 4; ++n) {
      const int col = n0 + wn * 64 + n * 16 + fr;
      const float bz = bias[col];
#pragma unroll
      for (int r = 0; r < 4; ++r) {
        const int row = m0 + wm * 32 + m * 16 + kg * 4 + r;
        Ob[(size_t)row * 4096 + col] = acc[m][n][r] + bz;
      }
    }
}

// ---------------------------------------------------------------------------
// Correlation partials over one t-half: grid (64 bh, 8 seg), 4 waves.
// Qc/Kc are half-buffers [bh][2048][64]; record index = bh*16 + segbase + seg.
// ---------------------------------------------------------------------------
__global__ __launch_bounds__(256)
void corr_partial(const float* __restrict__ Qc, const float* __restrict__ Kc,
                  float* __restrict__ P, int segbase)
{
  __shared__ float qs[4][16][64];    // 16 KB; reused as cbuf[64][64] after loop
  __shared__ float ks[4][16][64];    // 16 KB
  __shared__ float ssum[4][4][64];   // 4 KB: per-wave {Sq,Sk,Sq2,Sk2}
  const int bh  = blockIdx.x;
  const int seg = blockIdx.y;
  const int tid = threadIdx.x;
  const int wid = tid >> 6, lane = tid & 63;
  const float* qb = Qc + (size_t)bh * 131072;   // [2048][64]
  const float* kb = Kc + (size_t)bh * 131072;
  const int ty = lane >> 3;    // 0..7 -> d rows ty*8..+8
  const int tx = lane & 7;     // 0..7 -> e cols tx*8..+8
  const int rr = lane >> 4;    // staging row base 0..3
  const int cq = lane & 15;    // staging float4 col

  float acc[8][8];
#pragma unroll
  for (int i = 0; i < 8; ++i)
#pragma unroll
    for (int j = 0; j < 8; ++j) acc[i][j] = 0.f;
  float sQ[4]  = {0,0,0,0}, sK[4]  = {0,0,0,0};
  float sQ2[4] = {0,0,0,0}, sK2[4] = {0,0,0,0};

  for (int c = 0; c < 4; ++c) {      // wave handles 4 chunks of 16 t
    const int tbase = seg * 256 + wid * 64 + c * 16;
    float4 qv[4], kv[4];
#pragma unroll
    for (int i = 0; i < 4; ++i) {
      const size_t g = (size_t)(tbase + rr + i*4) * 64 + cq * 4;
      qv[i] = *(const float4*)&qb[g];
      kv[i] = *(const float4*)&kb[g];
    }
#pragma unroll
    for (int i = 0; i < 4; ++i) {
      const int row = rr + i*4;
      *(float4*)&qs[wid][row][cq*4] = qv[i];
      *(float4*)&ks[wid][row][cq*4] = kv[i];
      sQ[0] += qv[i].x; sQ[1] += qv[i].y; sQ[2] += qv[i].z; sQ[3] += qv[i].w;
      sK[0] += kv[i].x; sK[1] += kv[i].y; sK[2] += kv[i].z; sK[3] += kv[i].w;
      sQ2[0] = fmaf(qv[i].x, qv[i].x, sQ2[0]); sQ2[1] = fmaf(qv[i].y, qv[i].y, sQ2[1]);
      sQ2[2] = fmaf(qv[i].z, qv[i].z, sQ2[2]); sQ2[3] = fmaf(qv[i].w, qv[i].w, sQ2[3]);
      sK2[0] = fmaf(kv[i].x, kv[i].x, sK2[0]); sK2[1] = fmaf(kv[i].y, kv[i].y, sK2[1]);
      sK2[2] = fmaf(kv[i].z, kv[i].z, sK2[2]); sK2[3] = fmaf(kv[i].w, kv[i].w, sK2[3]);
    }
#pragma unroll 8
    for (int t = 0; t < 16; ++t) {
      const float4 qa  = *(const float4*)&qs[wid][t][ty*8];
      const float4 qb4 = *(const float4*)&qs[wid][t][ty*8+4];
      const float4 ka  = *(const float4*)&ks[wid][t][tx*8];
      const float4 kb4 = *(const float4*)&ks[wid][t][tx*8+4];
      const float av[8] = {qa.x, qa.y, qa.z, qa.w, qb4.x, qb4.y, qb4.z, qb4.w};
      const float bv[8] = {ka.x, ka.y, ka.z, ka.w, kb4.x, kb4.y, kb4.z, kb4.w};
#pragma unroll
      for (int i = 0; i < 8; ++i)
#pragma unroll
        for (int j = 0; j < 8; ++j)
          acc[i][j] = fmaf(av[i], bv[j], acc[i][j]);
    }
  }

  // per-wave sum reduce across lanes {cq, cq+16, cq+32, cq+48}
#pragma unroll
  for (int j = 0; j < 4; ++j) {
    sQ[j]  += __shfl_xor(sQ[j], 16, 64);  sQ[j]  += __shfl_xor(sQ[j], 32, 64);
    sK[j]  += __shfl_xor(sK[j], 16, 64);  sK[j]  += __shfl_xor(sK[j], 32, 64);
    sQ2[j] += __shfl_xor(sQ2[j], 16, 64); sQ2[j] += __shfl_xor(sQ2[j], 32, 64);
    sK2[j] += __shfl_xor(sK2[j], 16, 64); sK2[j] += __shfl_xor(sK2[j], 32, 64);
  }
  if (lane < 16) {
    float4 q4; q4.x = sQ[0];  q4.y = sQ[1];  q4.z = sQ[2];  q4.w = sQ[3];
    float4 k4; k4.x = sK[0];  k4.y = sK[1];  k4.z = sK[2];  k4.w = sK[3];
    float4 q2; q2.x = sQ2[0]; q2.y = sQ2[1]; q2.z = sQ2[2]; q2.w = sQ2[3];
    float4 k2; k2.x = sK2[0]; k2.y = sK2[1]; k2.z = sK2[2]; k2.w = sK2[3];
    *(float4*)&ssum[wid][0][lane*4] = q4;
    *(float4*)&ssum[wid][1][lane*4] = k4;
    *(float4*)&ssum[wid][2][lane*4] = q2;
    *(float4*)&ssum[wid][3][lane*4] = k2;
  }

  // cross-wave c reduction into cbuf (overlays qs; all staging reads done)
  float* cbuf = &qs[0][0][0];
  __syncthreads();
#pragma unroll
  for (int w = 0; w < 4; ++w) {
    if (wid == w) {
#pragma unroll
      for (int i = 0; i < 8; ++i) {
        float* p0 = &cbuf[(ty*8 + i) * 64 + tx*8];
        if (w == 0) {
          float4 o0, o1;
          o0.x = acc[i][0]; o0.y = acc[i][1]; o0.z = acc[i][2]; o0.w = acc[i][3];
          o1.x = acc[i][4]; o1.y = acc[i][5]; o1.z = acc[i][6]; o1.w = acc[i][7];
          *(float4*)p0 = o0; *(float4*)(p0 + 4) = o1;
        } else {
          float4 o0 = *(const float4*)p0, o1 = *(const float4*)(p0 + 4);
          o0.x += acc[i][0]; o0.y += acc[i][1]; o0.z += acc[i][2]; o0.w += acc[i][3];
          o1.x += acc[i][4]; o1.y += acc[i][5]; o1.z += acc[i][6]; o1.w += acc[i][7];
          *(float4*)p0 = o0; *(float4*)(p0 + 4) = o1;
        }
      }
    }
    __syncthreads();
  }

  // write record: 4096 c + 256 sums
  float* Pb = P + (size_t)(bh * 16 + segbase + seg) * 4352;
#pragma unroll
  for (int i = 0; i < 4; ++i)
    ((float4*)Pb)[tid + 256*i] = ((const float4*)cbuf)[tid + 256*i];
  {
    const int comp = tid >> 6, d = tid & 63;
    Pb[4096 + tid] = ssum[0][comp][d] + ssum[1][comp][d] +
                     ssum[2][comp][d] + ssum[3][comp][d];
  }
}

// ---------------------------------------------------------------------------
// Finalize: sum 16 segment partials; corr = clip((c-SqSk/T)/sqrt(sx*sy),-1,1)
// grid (64 bh, 4 quarters); sums re-read per block.
// ---------------------------------------------------------------------------
__global__ __launch_bounds__(256)
void corr_finalize(const float* __restrict__ P, float* __restrict__ corr)
{
  __shared__ float fin[4][64];
  const int bh = blockIdx.x, qtr = blockIdx.y;
  const int tid = threadIdx.x;
  const float* Pb = P + (size_t)bh * 16 * 4352;

  float s = 0.f;
  for (int seg = 0; seg < 16; ++seg) s += Pb[(size_t)seg*4352 + 4096 + tid];
  fin[tid >> 6][tid & 63] = s;

  float cacc[4] = {0.f, 0.f, 0.f, 0.f};
  for (int seg = 0; seg < 16; ++seg) {
#pragma unroll
    for (int i = 0; i < 4; ++i)
      cacc[i] += Pb[(size_t)seg*4352 + qtr*1024 + tid + i*256];
  }
  __syncthreads();

  const float invT = 1.0f / (float)TDIM;
#pragma unroll
  for (int i = 0; i < 4; ++i) {
    const int f = qtr*1024 + tid + i*256;
    const int d = f >> 6, e = f & 63;
    const float sq = fin[0][d], sk = fin[1][e];
    const float sq2 = fin[2][d], sk2 = fin[3][e];
    const float cc = cacc[i] - sq * sk * invT;
    const float sx = sq2 - sq * sq * invT;
    const float sy = sk2 - sk * sk * invT;
    float v = cc / sqrtf(sx * sy);
    v = fminf(1.f, fmaxf(-1.f, v));
    corr[(size_t)bh * 4096 + f] = v;
  }
}

// ---------------------------------------------------------------------------
// Weff_b[n][h*64+d] = sum_e corr[b,h][d][e] * Wout[n][h*64+e]
// Writes bf16 hi/lo directly (split fused).
// ---------------------------------------------------------------------------
__global__ __launch_bounds__(256)
void weff_kernel(const float* __restrict__ corr, const float* __restrict__ Wout,
                 ushort* __restrict__ Weh, ushort* __restrict__ Wel)
{
  __shared__ float cs[64][64];
  __shared__ float ws[128][64];
  const int bh = blockIdx.x;
  const int b = bh >> 4, h = bh & 15;
  const int n0 = blockIdx.y * 128;
  const int tid = threadIdx.x;

  const float* cb = corr + (size_t)bh * 4096;
  float4* csv = (float4*)&cs[0][0];
#pragma unroll
  for (int i = 0; i < 4; ++i)
    csv[tid + 256*i] = ((const float4*)cb)[tid + 256*i];

  const int wr = tid >> 1, wh = (tid & 1) * 32;
  const float* wrow = Wout + (size_t)(n0 + wr) * DDIM + h * HD + wh;
#pragma unroll
  for (int i = 0; i < 8; ++i)
    *(float4*)&ws[wr][wh + i*4] = *(const float4*)&wrow[i*4];
  __syncthreads();

  const int ni = (tid >> 3) * 4;
  const int di = (tid & 7) * 8;
  float acc[4][8];
#pragma unroll
  for (int i = 0; i < 4; ++i)
#pragma unroll
    for (int j = 0; j < 8; ++j) acc[i][j] = 0.f;

  for (int e = 0; e < 64; ++e) {
    float wv[4], cv[8];
#pragma unroll
    for (int i = 0; i < 4; ++i) wv[i] = ws[ni + i][e];
#pragma unroll
    for (int j = 0; j < 8; ++j) cv[j] = cs[di + j][e];
#pragma unroll
    for (int i = 0; i < 4; ++i)
#pragma unroll
      for (int j = 0; j < 8; ++j)
        acc[i][j] = fmaf(wv[i], cv[j], acc[i][j]);
  }

  const size_t base = (size_t)b * DDIM * DDIM + h * HD;
#pragma unroll
  for (int i = 0; i < 4; ++i) {
    ushort4 h0, l0, h1, l1;
    h0.x = f2bfu(acc[i][0]); l0.x = f2bfu(acc[i][0] - bfu2f(h0.x));
    h0.y = f2bfu(acc[i][1]); l0.y = f2bfu(acc[i][1] - bfu2f(h0.y));
    h0.z = f2bfu(acc[i][2]); l0.z = f2bfu(acc[i][2] - bfu2f(h0.z));
    h0.w = f2bfu(acc[i][3]); l0.w = f2bfu(acc[i][3] - bfu2f(h0.w));
    h1.x = f2bfu(acc[i][4]); l1.x = f2bfu(acc[i][4] - bfu2f(h1.x));
    h1.y = f2bfu(acc[i][5]); l1.y = f2bfu(acc[i][5] - bfu2f(h1.y));
    h1.z = f2bfu(acc[i][6]); l1.z = f2bfu(acc[i][6] - bfu2f(h1.z));
    h1.w = f2bfu(acc[i][7]); l1.w = f2bfu(acc[i][7] - bfu2f(h1.w));
    const size_t o = base + (size_t)(n0 + ni + i) * DDIM + di;
    *(ushort4*)&Weh[o]     = h0;
    *(ushort4*)&Weh[o + 4] = h1;
    *(ushort4*)&Wel[o]     = l0;
    *(ushort4*)&Wel[o + 4] = l1;
  }
}

// ---------------------------------------------------------------------------
extern "C" void kernel_launch(void* const* d_in, const int* in_sizes, int n_in,
                              void* d_out, int out_size, void* d_ws, size_t ws_size,
                              hipStream_t stream)
{
  (void)in_sizes; (void)n_in; (void)out_size; (void)ws_size;
  const float* x    = (const float*)d_in[0];
  const float* Wqkv = (const float*)d_in[1];
  const float* bqkv = (const float*)d_in[2];
  const float* Wout = (const float*)d_in[3];
  const float* bout = (const float*)d_in[4];
  float* out = (float*)d_out;

  // ws layout (bytes), total 236,978,176 B = 226.0 MiB (== r2-proven size)
  //  Xh, Xl   bf16 [16384][1024]                 32+32 MiB
  //  Qch, Kch fp32 [64 bh][2048 t_half][64]      32+32 MiB (half-buffers)
  //  Vh, Vl   bf16 [16384][1024]                 32+32 MiB
  //  corrB    fp32 [64][64][64]                  1 MiB
  //  R1: P (partials)                            17 MiB
  //  R2: phase A Wqh/Wql (12.6M) -> phase B Weh/Wel (16M)
  char* w = (char*)d_ws;
  ushort* Xh    = (ushort*)w;  w += (size_t)33554432;
  ushort* Xl    = (ushort*)w;  w += (size_t)33554432;
  float*  Qch   = (float*)w;   w += (size_t)33554432;
  float*  Kch   = (float*)w;   w += (size_t)33554432;
  ushort* Vh    = (ushort*)w;  w += (size_t)33554432;
  ushort* Vl    = (ushort*)w;  w += (size_t)33554432;
  float*  corrB = (float*)w;   w += (size_t)1048576;
  float*  P     = (float*)w;   w += (size_t)17825792;
  char* R2 = w;
  ushort* Wqh   = (ushort*)R2;
  ushort* Wql   = Wqh + (size_t)3145728;
  ushort* Weh   = (ushort*)R2;
  ushort* Wel   = Weh + (size_t)4194304;

  // 1) pre-split x and Wqkv -> bf16 hi/lo
  split_f32<<<dim3(2048), 256, 0, stream>>>(x, Xh, Xl, 4194304);
  split_f32<<<dim3(1024), 256, 0, stream>>>(Wqkv, Wqh, Wql, 786432);
  // 2) half 0: qkv GEMM (m 0..8191) then its 8 corr segments
  gemm1_mfma<<<dim3(24, 64), 256, 0, stream>>>(Xh, Xl, Wqh, Wql, bqkv,
                                               Qch, Kch, Vh, Vl, 0);
  corr_partial<<<dim3(64, 8), 256, 0, stream>>>(Qch, Kch, P, 0);
  // 3) half 1: qkv GEMM (m 8192..16383) reuses Qch/Kch, segments 8..15
  gemm1_mfma<<<dim3(24, 64), 256, 0, stream>>>(Xh, Xl, Wqh, Wql, bqkv,
                                               Qch, Kch, Vh, Vl, 8192);
  corr_partial<<<dim3(64, 8), 256, 0, stream>>>(Qch, Kch, P, 8);
  // 4) finalize corr
  corr_finalize<<<dim3(64, 4), 256, 0, stream>>>(P, corrB);
  // 5) Weff_b = fold(corr_b, Wout) -> bf16 hi/lo (overwrites Wq splits - dead)
  weff_kernel<<<dim3(64, 8), 256, 0, stream>>>(corrB, Wout, Weh, Wel);
  // 6) out = v @ Weff_b^T + bout (batched over b)
  gemm2_mfma<<<dim3(8, 64, 4), 256, 0, stream>>>(Vh, Vl, Weh, Wel, bout, out);
}

// Round 8
// 665.818 us; speedup vs baseline: 1.0590x; 1.0590x over previous
//
#include <hip/hip_runtime.h>
#include <hip/hip_bf16.h>

// Problem constants (fixed by setup_inputs)
#define TDIM 4096
#define BDIM 4
#define DDIM 1024
#define HDIM 16
#define HD   64
#define MDIM (TDIM * BDIM)      // 16384 rows (t,b)

typedef __attribute__((ext_vector_type(8))) short short8v;  // 8 bf16 bits = 4 VGPR
typedef __attribute__((ext_vector_type(4))) float f32x4;

__device__ __forceinline__ ushort f2bfu(float f) {
  union { __hip_bfloat16 h; ushort u; } c;
  c.h = __float2bfloat16(f);
  return c.u;
}
__device__ __forceinline__ float bfu2f(ushort u) {
  union { ushort u; __hip_bfloat16 h; } c;
  c.u = u;
  return __bfloat162float(c.h);
}

// async global->LDS, 16B per lane; LDS dest = wave-uniform base + lane*16
#define GLOAD16(gp, lp) __builtin_amdgcn_global_load_lds( \
    (const __attribute__((address_space(1))) void*)(gp),  \
    (__attribute__((address_space(3))) void*)(lp), 16, 0, 0)

// LDS swizzle: g(row) = (row>>1)&3. Bank quad = 4*(row&1) + (slot^g(row))
// is bijective over 8 consecutive rows -> 2 lanes/quad on ds_read_b128 (free).
// Verified r4: SQ_LDS_BANK_CONFLICT 2.5e7 -> 0.
#define SWZ(row) (((row) >> 1) & 3)

// ---------------------------------------------------------------------------
// split fp32 -> bf16 hi/lo arrays (hi = bf16(x), lo = bf16(x - hi))
// ---------------------------------------------------------------------------
__global__ __launch_bounds__(256)
void split_f32(const float* __restrict__ in, ushort* __restrict__ hi,
               ushort* __restrict__ lo, int n4)
{
  int i = blockIdx.x * blockDim.x + threadIdx.x;
  const int stride = gridDim.x * blockDim.x;
  for (; i < n4; i += stride) {
    const float4 v = ((const float4*)in)[i];
    ushort4 h, l;
    h.x = f2bfu(v.x); l.x = f2bfu(v.x - bfu2f(h.x));
    h.y = f2bfu(v.y); l.y = f2bfu(v.y - bfu2f(h.y));
    h.z = f2bfu(v.z); l.z = f2bfu(v.z - bfu2f(h.z));
    h.w = f2bfu(v.w); l.w = f2bfu(v.w - bfu2f(h.w));
    ((ushort4*)hi)[i] = h;
    ((ushort4*)lo)[i] = l;
  }
}

// ---------------------------------------------------------------------------
// GEMM1 (r8): r6 operand structure (A = x fp32 reg-staged + split on the fly
// -- the split VALU co-issues with MFMA per m114; r7 proved removing it HURTS)
// + T3/T4 minimum 2-phase pipeline: double-buffered LDS, next-tile loads
// ISSUED BEFORE current-tile MFMA, A convert+ds_write AFTER MFMA, ONE barrier
// per K-step (its vmcnt(0) drain lands after the MFMAs -> load latency hidden
// under compute instead of serialized before it).
// Output: q -> Qc[bh][t][64] fp32 (head-major); k -> Kc; v -> bf16 hi/lo V.
// 128x128 tile, BK=32, 4 waves (2x2), each wave 4x4 frags of 16x16x32.
// ---------------------------------------------------------------------------
__global__ __launch_bounds__(256, 2)
void gemm1_mfma(const float* __restrict__ X, const ushort* __restrict__ Wh,
                const ushort* __restrict__ Wl, const float* __restrict__ bias,
                float* __restrict__ Qc, float* __restrict__ Kc,
                ushort* __restrict__ Vh, ushort* __restrict__ Vl)
{
  __shared__ ushort sAh[2][128][32], sAl[2][128][32];
  __shared__ ushort sBh[2][128][32], sBl[2][128][32];
  const int tid = threadIdx.x;
  const int lane = tid & 63, wid = tid >> 6;
  const int m0 = blockIdx.y * 128, n0 = blockIdx.x * 128;
  const int ar = tid >> 3, aq = tid & 7;       // A staging: row base, float4 slot
  const int wm = wid >> 1, wn = wid & 1;       // wave grid 2x2
  const int fr = lane & 15, kg = lane >> 4;    // frag row/col, k-group

  f32x4 acc[4][4];
#pragma unroll
  for (int m = 0; m < 4; ++m)
#pragma unroll
    for (int n = 0; n < 4; ++n) acc[m][n] = (f32x4){0.f, 0.f, 0.f, 0.f};

  // ---- prologue: stage tile 0 into buf 0 ----
  {
    float4 av[4];
#pragma unroll
    for (int i = 0; i < 4; ++i)
      av[i] = *(const float4*)&X[(size_t)(m0 + ar + i * 32) * DDIM + aq * 4];
#pragma unroll
    for (int j = 0; j < 4; ++j) {
      const int c = wid * 4 + j;                 // 16 chunks: 8 Bh + 8 Bl
      const int r0 = (c & 7) * 16;
      const int row = r0 + (lane >> 2);
      const int s = lane & 3;
      const size_t goff = (size_t)(n0 + row) * DDIM + ((s ^ SWZ(row)) << 3);
      if (c < 8) GLOAD16(Wh + goff, &sBh[0][r0][0]);
      else       GLOAD16(Wl + goff, &sBl[0][r0][0]);
    }
#pragma unroll
    for (int i = 0; i < 4; ++i) {
      const int row = ar + i * 32;
      const int sl = (((aq >> 1) ^ SWZ(row)) << 3) + ((aq & 1) << 2);
      ushort4 hv, lv;
      hv.x = f2bfu(av[i].x); lv.x = f2bfu(av[i].x - bfu2f(hv.x));
      hv.y = f2bfu(av[i].y); lv.y = f2bfu(av[i].y - bfu2f(hv.y));
      hv.z = f2bfu(av[i].z); lv.z = f2bfu(av[i].z - bfu2f(hv.z));
      hv.w = f2bfu(av[i].w); lv.w = f2bfu(av[i].w - bfu2f(hv.w));
      *(ushort4*)&sAh[0][row][sl] = hv;
      *(ushort4*)&sAl[0][row][sl] = lv;
    }
    __syncthreads();   // buf0 ready (vmcnt+lgkm drained by syncthreads)
  }

  int cur = 0;
  for (int k0 = 0; k0 < DDIM; k0 += 32) {
    const int nxt = cur ^ 1;
    const bool has_next = (k0 + 32 < DDIM);
    float4 av[4];
    if (has_next) {
      // ---- issue next tile's loads FIRST (drained only after the MFMAs) ----
#pragma unroll
      for (int j = 0; j < 4; ++j) {
        const int c = wid * 4 + j;
        const int r0 = (c & 7) * 16;
        const int row = r0 + (lane >> 2);
        const int s = lane & 3;
        const size_t goff = (size_t)(n0 + row) * DDIM + k0 + 32 + ((s ^ SWZ(row)) << 3);
        if (c < 8) GLOAD16(Wh + goff, &sBh[nxt][r0][0]);
        else       GLOAD16(Wl + goff, &sBl[nxt][r0][0]);
      }
#pragma unroll
      for (int i = 0; i < 4; ++i)
        av[i] = *(const float4*)&X[(size_t)(m0 + ar + i * 32) * DDIM + k0 + 32 + aq * 4];
    }

    // ---- compute tile k0 from buf[cur]: 16 ds_read_b128 + 48 MFMA / wave ----
    short8v ah[4], al[4], bh[4], bl[4];
#pragma unroll
    for (int m = 0; m < 4; ++m) {
      const int row = wm * 64 + m * 16 + fr;
      const int so = (kg ^ SWZ(row)) << 3;
      ah[m] = *(const short8v*)&sAh[cur][row][so];
      al[m] = *(const short8v*)&sAl[cur][row][so];
    }
#pragma unroll
    for (int n = 0; n < 4; ++n) {
      const int col = wn * 64 + n * 16 + fr;
      const int so = (kg ^ SWZ(col)) << 3;
      bh[n] = *(const short8v*)&sBh[cur][col][so];
      bl[n] = *(const short8v*)&sBl[cur][col][so];
    }
#pragma unroll
    for (int m = 0; m < 4; ++m)
#pragma unroll
      for (int n = 0; n < 4; ++n) {
        acc[m][n] = __builtin_amdgcn_mfma_f32_16x16x32_bf16(ah[m], bh[n], acc[m][n], 0, 0, 0);
        acc[m][n] = __builtin_amdgcn_mfma_f32_16x16x32_bf16(ah[m], bl[n], acc[m][n], 0, 0, 0);
        acc[m][n] = __builtin_amdgcn_mfma_f32_16x16x32_bf16(al[m], bh[n], acc[m][n], 0, 0, 0);
      }

    if (has_next) {
      // ---- convert + ds_write A into buf[nxt] (after MFMA; the implicit
      //      vmcnt wait for av also drains the B gloads -- post-compute) ----
#pragma unroll
      for (int i = 0; i < 4; ++i) {
        const int row = ar + i * 32;
        const int sl = (((aq >> 1) ^ SWZ(row)) << 3) + ((aq & 1) << 2);
        ushort4 hv, lv;
        hv.x = f2bfu(av[i].x); lv.x = f2bfu(av[i].x - bfu2f(hv.x));
        hv.y = f2bfu(av[i].y); lv.y = f2bfu(av[i].y - bfu2f(hv.y));
        hv.z = f2bfu(av[i].z); lv.z = f2bfu(av[i].z - bfu2f(hv.z));
        hv.w = f2bfu(av[i].w); lv.w = f2bfu(av[i].w - bfu2f(hv.w));
        *(ushort4*)&sAh[nxt][row][sl] = hv;
        *(ushort4*)&sAl[nxt][row][sl] = lv;
      }
    }
    __syncthreads();   // one barrier/iter: t's reads done before t+1 overwrites
    cur = nxt;
  }

  // ---- epilogue: C/D layout col=lane&15, row=(lane>>4)*4+reg (m89) ----
  const int region = n0 >> 10;   // 0=q, 1=k, 2=v (128-tiles never straddle)
#pragma unroll
  for (int m = 0; m < 4; ++m)
#pragma unroll
    for (int n = 0; n < 4; ++n) {
      const int col = n0 + wn * 64 + n * 16 + fr;
      const float bz = bias[col];
      const int cc = col & 1023;
      const int hh = cc >> 6, dd = cc & 63;
#pragma unroll
      for (int r = 0; r < 4; ++r) {
        const int row = m0 + wm * 64 + m * 16 + kg * 4 + r;
        const float v = acc[m][n][r] + bz;
        const int t = row >> 2, b = row & 3;     // rows are (t,b) interleaved
        const size_t ho = (((size_t)(b * 16 + hh)) * 4096 + t) * 64 + dd;
        if (region == 0)      Qc[ho] = v;
        else if (region == 1) Kc[ho] = v;
        else {
          const size_t o = (size_t)row * 1024 + cc;
          const ushort h2 = f2bfu(v);
          Vh[o] = h2;
          Vl[o] = f2bfu(v - bfu2f(h2));
        }
      }
    }
}

// ---------------------------------------------------------------------------
// GEMM2 (batched over b): out[t,b,:] = v[t,b,:] @ Weff_b^T + bout.
// BM=64, BN=128, grid (8, 64, 4) = 2048 blocks. Unchanged from r6.
// ---------------------------------------------------------------------------
__global__ __launch_bounds__(256, 2)
void gemm2_mfma(const ushort* __restrict__ Vh, const ushort* __restrict__ Vl,
                const ushort* __restrict__ Weh, const ushort* __restrict__ Wel,
                const float* __restrict__ bias, float* __restrict__ Out)
{
  __shared__ ushort sAh[64][32], sAl[64][32], sBh[128][32], sBl[128][32];
  const int tid = threadIdx.x;
  const int lane = tid & 63, wid = tid >> 6;
  const int m0 = blockIdx.y * 64, n0 = blockIdx.x * 128, bb = blockIdx.z;
  const int wm = wid >> 1, wn = wid & 1;
  const int fr = lane & 15, kg = lane >> 4;

  f32x4 acc[2][4];
#pragma unroll
  for (int m = 0; m < 2; ++m)
#pragma unroll
    for (int n = 0; n < 4; ++n) acc[m][n] = (f32x4){0.f, 0.f, 0.f, 0.f};

  const size_t wB = (size_t)bb * DDIM * DDIM;

  for (int k0 = 0; k0 < DDIM; k0 += 32) {
#pragma unroll
    for (int j = 0; j < 6; ++j) {
      const int c = wid * 6 + j;
      const int rl = lane >> 2, s = lane & 3;
      if (c < 8) {
        const int r0 = (c & 3) * 16;
        const int row = r0 + rl;
        const size_t g = (size_t)((m0 + row) * 4 + bb) * 1024 + k0 + ((s ^ SWZ(row)) << 3);
        if (c < 4) GLOAD16(Vh + g, &sAh[r0][0]);
        else       GLOAD16(Vl + g, &sAl[r0][0]);
      } else {
        const int r0 = ((c - 8) & 7) * 16;
        const int row = r0 + rl;
        const size_t g = wB + (size_t)(n0 + row) * 1024 + k0 + ((s ^ SWZ(row)) << 3);
        if (c < 16) GLOAD16(Weh + g, &sBh[r0][0]);
        else        GLOAD16(Wel + g, &sBl[r0][0]);
      }
    }
    __syncthreads();

    short8v ah[2], al[2], bh[4], bl[4];
#pragma unroll
    for (int m = 0; m < 2; ++m) {
      const int row = wm * 32 + m * 16 + fr;
      const int so = (kg ^ SWZ(row)) << 3;
      ah[m] = *(const short8v*)&sAh[row][so];
      al[m] = *(const short8v*)&sAl[row][so];
    }
#pragma unroll
    for (int n = 0; n < 4; ++n) {
      const int col = wn * 64 + n * 16 + fr;
      const int so = (kg ^ SWZ(col)) << 3;
      bh[n] = *(const short8v*)&sBh[col][so];
      bl[n] = *(const short8v*)&sBl[col][so];
    }
#pragma unroll
    for (int m = 0; m < 2; ++m)
#pragma unroll
      for (int n = 0; n < 4; ++n) {
        acc[m][n] = __builtin_amdgcn_mfma_f32_16x16x32_bf16(ah[m], bh[n], acc[m][n], 0, 0, 0);
        acc[m][n] = __builtin_amdgcn_mfma_f32_16x16x32_bf16(ah[m], bl[n], acc[m][n], 0, 0, 0);
        acc[m][n] = __builtin_amdgcn_mfma_f32_16x16x32_bf16(al[m], bh[n], acc[m][n], 0, 0, 0);
      }
    __syncthreads();
  }

  float* Ob = Out + (size_t)bb * 1024;     // row t -> offset t*4096
#pragma unroll
  for (int m = 0; m < 2; ++m)
#pragma unroll
    for (int n = 0; n < 4; ++n) {
      const int col = n0 + wn * 64 + n * 16 + fr;
      const float bz = bias[col];
#pragma unroll
      for (int r = 0; r < 4; ++r) {
        const int row = m0 + wm * 32 + m * 16 + kg * 4 + r;
        Ob[(size_t)row * 4096 + col] = acc[m][n][r] + bz;
      }
    }
}

// ---------------------------------------------------------------------------
// Correlation partials: grid (64 bh, 16 seg), 256 threads = 4 waves.
// Head-major Qc/Kc -> each block streams contiguous 64KB q + 64KB k.
// Wave-private staging slices, no barriers in the t-loop.
// Record: 4096 c + 256 sums = 4352 floats (layout unchanged).
// ---------------------------------------------------------------------------
__global__ __launch_bounds__(256)
void corr_partial(const float* __restrict__ Qc, const float* __restrict__ Kc,
                  float* __restrict__ P)
{
  __shared__ float qs[4][16][64];    // 16 KB; reused as cbuf[64][64] after loop
  __shared__ float ks[4][16][64];    // 16 KB
  __shared__ float ssum[4][4][64];   // 4 KB: per-wave {Sq,Sk,Sq2,Sk2}
  const int bh  = blockIdx.x;
  const int seg = blockIdx.y;
  const int tid = threadIdx.x;
  const int wid = tid >> 6, lane = tid & 63;
  const float* qb = Qc + (size_t)bh * 262144;   // [4096][64]
  const float* kb = Kc + (size_t)bh * 262144;
  const int ty = lane >> 3;    // 0..7 -> d rows ty*8..+8
  const int tx = lane & 7;     // 0..7 -> e cols tx*8..+8
  const int rr = lane >> 4;    // staging row base 0..3
  const int cq = lane & 15;    // staging float4 col

  float acc[8][8];
#pragma unroll
  for (int i = 0; i < 8; ++i)
#pragma unroll
    for (int j = 0; j < 8; ++j) acc[i][j] = 0.f;
  float sQ[4]  = {0,0,0,0}, sK[4]  = {0,0,0,0};
  float sQ2[4] = {0,0,0,0}, sK2[4] = {0,0,0,0};

  for (int c = 0; c < 4; ++c) {      // wave handles 4 chunks of 16 t
    const int tbase = seg * 256 + wid * 64 + c * 16;
    float4 qv[4], kv[4];
#pragma unroll
    for (int i = 0; i < 4; ++i) {
      const size_t g = (size_t)(tbase + rr + i*4) * 64 + cq * 4;
      qv[i] = *(const float4*)&qb[g];
      kv[i] = *(const float4*)&kb[g];
    }
#pragma unroll
    for (int i = 0; i < 4; ++i) {
      const int row = rr + i*4;
      *(float4*)&qs[wid][row][cq*4] = qv[i];
      *(float4*)&ks[wid][row][cq*4] = kv[i];
      sQ[0] += qv[i].x; sQ[1] += qv[i].y; sQ[2] += qv[i].z; sQ[3] += qv[i].w;
      sK[0] += kv[i].x; sK[1] += kv[i].y; sK[2] += kv[i].z; sK[3] += kv[i].w;
      sQ2[0] = fmaf(qv[i].x, qv[i].x, sQ2[0]); sQ2[1] = fmaf(qv[i].y, qv[i].y, sQ2[1]);
      sQ2[2] = fmaf(qv[i].z, qv[i].z, sQ2[2]); sQ2[3] = fmaf(qv[i].w, qv[i].w, sQ2[3]);
      sK2[0] = fmaf(kv[i].x, kv[i].x, sK2[0]); sK2[1] = fmaf(kv[i].y, kv[i].y, sK2[1]);
      sK2[2] = fmaf(kv[i].z, kv[i].z, sK2[2]); sK2[3] = fmaf(kv[i].w, kv[i].w, sK2[3]);
    }
#pragma unroll 8
    for (int t = 0; t < 16; ++t) {
      const float4 qa  = *(const float4*)&qs[wid][t][ty*8];
      const float4 qb4 = *(const float4*)&qs[wid][t][ty*8+4];
      const float4 ka  = *(const float4*)&ks[wid][t][tx*8];
      const float4 kb4 = *(const float4*)&ks[wid][t][tx*8+4];
      const float av[8] = {qa.x, qa.y, qa.z, qa.w, qb4.x, qb4.y, qb4.z, qb4.w};
      const float bv[8] = {ka.x, ka.y, ka.z, ka.w, kb4.x, kb4.y, kb4.z, kb4.w};
#pragma unroll
      for (int i = 0; i < 8; ++i)
#pragma unroll
        for (int j = 0; j < 8; ++j)
          acc[i][j] = fmaf(av[i], bv[j], acc[i][j]);
    }
  }

  // per-wave sum reduce across lanes {cq, cq+16, cq+32, cq+48}
#pragma unroll
  for (int j = 0; j < 4; ++j) {
    sQ[j]  += __shfl_xor(sQ[j], 16, 64);  sQ[j]  += __shfl_xor(sQ[j], 32, 64);
    sK[j]  += __shfl_xor(sK[j], 16, 64);  sK[j]  += __shfl_xor(sK[j], 32, 64);
    sQ2[j] += __shfl_xor(sQ2[j], 16, 64); sQ2[j] += __shfl_xor(sQ2[j], 32, 64);
    sK2[j] += __shfl_xor(sK2[j], 16, 64); sK2[j] += __shfl_xor(sK2[j], 32, 64);
  }
  if (lane < 16) {
    float4 q4; q4.x = sQ[0];  q4.y = sQ[1];  q4.z = sQ[2];  q4.w = sQ[3];
    float4 k4; k4.x = sK[0];  k4.y = sK[1];  k4.z = sK[2];  k4.w = sK[3];
    float4 q2; q2.x = sQ2[0]; q2.y = sQ2[1]; q2.z = sQ2[2]; q2.w = sQ2[3];
    float4 k2; k2.x = sK2[0]; k2.y = sK2[1]; k2.z = sK2[2]; k2.w = sK2[3];
    *(float4*)&ssum[wid][0][lane*4] = q4;
    *(float4*)&ssum[wid][1][lane*4] = k4;
    *(float4*)&ssum[wid][2][lane*4] = q2;
    *(float4*)&ssum[wid][3][lane*4] = k2;
  }

  // cross-wave c reduction into cbuf (overlays qs; all staging reads done)
  float* cbuf = &qs[0][0][0];
  __syncthreads();
#pragma unroll
  for (int w = 0; w < 4; ++w) {
    if (wid == w) {
#pragma unroll
      for (int i = 0; i < 8; ++i) {
        float* p0 = &cbuf[(ty*8 + i) * 64 + tx*8];
        if (w == 0) {
          float4 o0, o1;
          o0.x = acc[i][0]; o0.y = acc[i][1]; o0.z = acc[i][2]; o0.w = acc[i][3];
          o1.x = acc[i][4]; o1.y = acc[i][5]; o1.z = acc[i][6]; o1.w = acc[i][7];
          *(float4*)p0 = o0; *(float4*)(p0 + 4) = o1;
        } else {
          float4 o0 = *(const float4*)p0, o1 = *(const float4*)(p0 + 4);
          o0.x += acc[i][0]; o0.y += acc[i][1]; o0.z += acc[i][2]; o0.w += acc[i][3];
          o1.x += acc[i][4]; o1.y += acc[i][5]; o1.z += acc[i][6]; o1.w += acc[i][7];
          *(float4*)p0 = o0; *(float4*)(p0 + 4) = o1;
        }
      }
    }
    __syncthreads();
  }

  // write record: 4096 c + 256 sums
  float* Pb = P + (size_t)(bh * 16 + seg) * 4352;
#pragma unroll
  for (int i = 0; i < 4; ++i)
    ((float4*)Pb)[tid + 256*i] = ((const float4*)cbuf)[tid + 256*i];
  {
    const int comp = tid >> 6, d = tid & 63;
    Pb[4096 + tid] = ssum[0][comp][d] + ssum[1][comp][d] +
                     ssum[2][comp][d] + ssum[3][comp][d];
  }
}

// ---------------------------------------------------------------------------
// Finalize: sum 16 segment partials; corr = clip((c-SqSk/T)/sqrt(sx*sy),-1,1)
// grid (64 bh, 4 quarters); sums re-read per block.
// ---------------------------------------------------------------------------
__global__ __launch_bounds__(256)
void corr_finalize(const float* __restrict__ P, float* __restrict__ corr)
{
  __shared__ float fin[4][64];
  const int bh = blockIdx.x, qtr = blockIdx.y;
  const int tid = threadIdx.x;
  const float* Pb = P + (size_t)bh * 16 * 4352;

  float s = 0.f;
  for (int seg = 0; seg < 16; ++seg) s += Pb[(size_t)seg*4352 + 4096 + tid];
  fin[tid >> 6][tid & 63] = s;

  float cacc[4] = {0.f, 0.f, 0.f, 0.f};
  for (int seg = 0; seg < 16; ++seg) {
#pragma unroll
    for (int i = 0; i < 4; ++i)
      cacc[i] += Pb[(size_t)seg*4352 + qtr*1024 + tid + i*256];
  }
  __syncthreads();

  const float invT = 1.0f / (float)TDIM;
#pragma unroll
  for (int i = 0; i < 4; ++i) {
    const int f = qtr*1024 + tid + i*256;
    const int d = f >> 6, e = f & 63;
    const float sq = fin[0][d], sk = fin[1][e];
    const float sq2 = fin[2][d], sk2 = fin[3][e];
    const float cc = cacc[i] - sq * sk * invT;
    const float sx = sq2 - sq * sq * invT;
    const float sy = sk2 - sk * sk * invT;
    float v = cc / sqrtf(sx * sy);
    v = fminf(1.f, fmaxf(-1.f, v));
    corr[(size_t)bh * 4096 + f] = v;
  }
}

// ---------------------------------------------------------------------------
// Weff_b[n][h*64+d] = sum_e corr[b,h][d][e] * Wout[n][h*64+e]
// Writes bf16 hi/lo directly (split fused).
// ---------------------------------------------------------------------------
__global__ __launch_bounds__(256)
void weff_kernel(const float* __restrict__ corr, const float* __restrict__ Wout,
                 ushort* __restrict__ Weh, ushort* __restrict__ Wel)
{
  __shared__ float cs[64][64];
  __shared__ float ws[128][64];
  const int bh = blockIdx.x;
  const int b = bh >> 4, h = bh & 15;
  const int n0 = blockIdx.y * 128;
  const int tid = threadIdx.x;

  const float* cb = corr + (size_t)bh * 4096;
  float4* csv = (float4*)&cs[0][0];
#pragma unroll
  for (int i = 0; i < 4; ++i)
    csv[tid + 256*i] = ((const float4*)cb)[tid + 256*i];

  const int wr = tid >> 1, wh = (tid & 1) * 32;
  const float* wrow = Wout + (size_t)(n0 + wr) * DDIM + h * HD + wh;
#pragma unroll
  for (int i = 0; i < 8; ++i)
    *(float4*)&ws[wr][wh + i*4] = *(const float4*)&wrow[i*4];
  __syncthreads();

  const int ni = (tid >> 3) * 4;
  const int di = (tid & 7) * 8;
  float acc[4][8];
#pragma unroll
  for (int i = 0; i < 4; ++i)
#pragma unroll
    for (int j = 0; j < 8; ++j) acc[i][j] = 0.f;

  for (int e = 0; e < 64; ++e) {
    float wv[4], cv[8];
#pragma unroll
    for (int i = 0; i < 4; ++i) wv[i] = ws[ni + i][e];
#pragma unroll
    for (int j = 0; j < 8; ++j) cv[j] = cs[di + j][e];
#pragma unroll
    for (int i = 0; i < 4; ++i)
#pragma unroll
      for (int j = 0; j < 8; ++j)
        acc[i][j] = fmaf(wv[i], cv[j], acc[i][j]);
  }

  const size_t base = (size_t)b * DDIM * DDIM + h * HD;
#pragma unroll
  for (int i = 0; i < 4; ++i) {
    ushort4 h0, l0, h1, l1;
    h0.x = f2bfu(acc[i][0]); l0.x = f2bfu(acc[i][0] - bfu2f(h0.x));
    h0.y = f2bfu(acc[i][1]); l0.y = f2bfu(acc[i][1] - bfu2f(h0.y));
    h0.z = f2bfu(acc[i][2]); l0.z = f2bfu(acc[i][2] - bfu2f(h0.z));
    h0.w = f2bfu(acc[i][3]); l0.w = f2bfu(acc[i][3] - bfu2f(h0.w));
    h1.x = f2bfu(acc[i][4]); l1.x = f2bfu(acc[i][4] - bfu2f(h1.x));
    h1.y = f2bfu(acc[i][5]); l1.y = f2bfu(acc[i][5] - bfu2f(h1.y));
    h1.z = f2bfu(acc[i][6]); l1.z = f2bfu(acc[i][6] - bfu2f(h1.z));
    h1.w = f2bfu(acc[i][7]); l1.w = f2bfu(acc[i][7] - bfu2f(h1.w));
    const size_t o = base + (size_t)(n0 + ni + i) * DDIM + di;
    *(ushort4*)&Weh[o]     = h0;
    *(ushort4*)&Weh[o + 4] = h1;
    *(ushort4*)&Wel[o]     = l0;
    *(ushort4*)&Wel[o + 4] = l1;
  }
}

// ---------------------------------------------------------------------------
extern "C" void kernel_launch(void* const* d_in, const int* in_sizes, int n_in,
                              void* d_out, int out_size, void* d_ws, size_t ws_size,
                              hipStream_t stream)
{
  (void)in_sizes; (void)n_in; (void)out_size; (void)ws_size;
  const float* x    = (const float*)d_in[0];
  const float* Wqkv = (const float*)d_in[1];
  const float* bqkv = (const float*)d_in[2];
  const float* Wout = (const float*)d_in[3];
  const float* bout = (const float*)d_in[4];
  float* out = (float*)d_out;

  // ws layout (bytes), total 220,200,960 B = 210.0 MiB (r6-proven)
  //  [0,64M)    Qc fp32 [64 bh][4096 t][64 d]   (head-major)
  //  [64M,128M) Kc fp32 [64 bh][4096 t][64 d]
  //  [+32M+32M) Vh, Vl bf16 [16384][1024]
  //  [+1M)      corr fp32 [64][64][64]
  //  R1 17.0M   phase A: Wqh/Wql (12.6M) -> phase B: P (17.0M)
  //  R2 16M     Weh/Wel bf16 [4][1024][1024]
  char* w = (char*)d_ws;
  float*  Qc    = (float*)w;   w += (size_t)67108864;
  float*  Kc    = (float*)w;   w += (size_t)67108864;
  ushort* Vh    = (ushort*)w;  w += (size_t)33554432;
  ushort* Vl    = (ushort*)w;  w += (size_t)33554432;
  float*  corrB = (float*)w;   w += (size_t)1048576;
  char* R1 = w;                w += (size_t)17825792;
  char* R2 = w;
  ushort* Wqh   = (ushort*)R1;
  ushort* Wql   = Wqh + (size_t)3145728;
  float*  P     = (float*)R1;
  ushort* Weh   = (ushort*)R2;
  ushort* Wel   = Weh + (size_t)4194304;

  // 1) split Wqkv -> bf16 hi/lo
  split_f32<<<dim3(1024), 256, 0, stream>>>(Wqkv, Wqh, Wql, 786432);
  // 2) qkv GEMM: q,k -> head-major fp32 Qc/Kc; v -> bf16 Vh/Vl
  gemm1_mfma<<<dim3(24, 128), 256, 0, stream>>>(x, Wqh, Wql, bqkv, Qc, Kc, Vh, Vl);
  // 3) correlation partials (P overwrites Wq splits - dead after GEMM1)
  corr_partial<<<dim3(64, 16), 256, 0, stream>>>(Qc, Kc, P);
  // 4) finalize corr
  corr_finalize<<<dim3(64, 4), 256, 0, stream>>>(P, corrB);
  // 5) Weff_b = fold(corr_b, Wout) -> bf16 hi/lo directly (split fused)
  weff_kernel<<<dim3(64, 8), 256, 0, stream>>>(corrB, Wout, Weh, Wel);
  // 6) out = v @ Weff_b^T + bout (batched over b; 2048 blocks)
  gemm2_mfma<<<dim3(8, 64, 4), 256, 0, stream>>>(Vh, Vl, Weh, Wel, bout, out);
}